// Round 7
// baseline (655.975 us; speedup 1.0000x reference)
//
#include <hip/hip_runtime.h>

#define TOK 32768          // B*N
#define DMODEL 1024
#define NSEQ 8192
#define NCHK 32            // chunks per sequence
#define CHUNKC 256
#define KDIM 1024
#define LOG2E 1.44269504f

typedef __attribute__((ext_vector_type(8))) short bf16x8;
typedef __attribute__((ext_vector_type(4))) float f32x4;

__device__ __forceinline__ unsigned short f2bf(float f) {
  unsigned u = __float_as_uint(f);
  u += 0x7fffu + ((u >> 16) & 1u);
  return (unsigned short)(u >> 16);
}
__device__ __forceinline__ float bf2f(unsigned short h) {
  return __uint_as_float(((unsigned)h) << 16);
}
__device__ __forceinline__ float sigm(float x) {   // sigmoid via exp2+rcp
  return __builtin_amdgcn_rcpf(1.f + exp2f(-LOG2E * x));
}

typedef __attribute__((address_space(3))) unsigned int lds_u32_t;
typedef const __attribute__((address_space(1))) unsigned int glb_u32_t;

__device__ __forceinline__ void gl_lds16(const void* g, void* l) {
  __builtin_amdgcn_global_load_lds((glb_u32_t*)g, (lds_u32_t*)l, 16, 0, 0);
}

// ---------------- weight transpose to bf16 (W[R][C] -> WT[C][R]) ----------------
__global__ __launch_bounds__(256) void transpose_bf16_k(const float* __restrict__ in,
                                                        unsigned short* __restrict__ out,
                                                        int R, int C) {
  __shared__ float tile[32][33];
  const int c0 = blockIdx.x * 32, r0 = blockIdx.y * 32;
  const int tx = threadIdx.x, ty = threadIdx.y;
#pragma unroll
  for (int i = 0; i < 32; i += 8)
    tile[ty + i][tx] = in[(long)(r0 + ty + i) * C + c0 + tx];
  __syncthreads();
#pragma unroll
  for (int i = 0; i < 32; i += 8)
    out[(long)(c0 + ty + i) * R + r0 + tx] = f2bf(tile[tx][ty + i]);
}

// ---------------- RoPE cos/sin table ----------------
__global__ __launch_bounds__(256) void ropetab_k(float2* __restrict__ tab) {
  const int i = blockIdx.x * 256 + threadIdx.x;   // 8192*32 entries
  const int f = i & 31, n = i >> 5;
  const float invf = exp2f(-(float)f * (13.287712379549449f / 32.0f)); // log2(10000)/32
  const float ang = (float)n * invf;
  tab[i] = make_float2(cosf(ang), sinf(ang));
}

// ---------------- fused RMSNorm + depthwise causal conv(K=4) + SiLU -> bf16 -------
__global__ __launch_bounds__(256) void rmsconv_k(const float* __restrict__ x,
                                                 const float* __restrict__ scale,
                                                 const float* __restrict__ w,
                                                 const float* __restrict__ cb,
                                                 unsigned short* __restrict__ xc) {
  __shared__ float xs[11][1024];   // rows row0-3 .. row0+7 normalized
  __shared__ float red[4];
  const int t = threadIdx.x;
  const long row0 = (long)blockIdx.x * 8;
  const bool seqstart = ((row0 & (NSEQ - 1)) == 0);
  const float4 sc = ((const float4*)scale)[t];
  for (int i = 0; i < 11; ++i) {
    if (i < 3 && seqstart) {            // block-uniform branch
      ((float4*)xs[i])[t] = make_float4(0.f, 0.f, 0.f, 0.f);
      continue;
    }
    const long r = row0 - 3 + i;
    const float4 v = ((const float4*)(x + r * DMODEL))[t];
    float ss = v.x * v.x + v.y * v.y + v.z * v.z + v.w * v.w;
#pragma unroll
    for (int off = 32; off > 0; off >>= 1) ss += __shfl_down(ss, off);
    if ((t & 63) == 0) red[t >> 6] = ss;
    __syncthreads();
    const float tot = red[0] + red[1] + red[2] + red[3];
    const float rr = rsqrtf(tot * (1.0f / DMODEL) + 1e-6f);
    float4 o;
    o.x = fminf(fmaxf(v.x * rr * sc.x, -60000.f), 60000.f);
    o.y = fminf(fmaxf(v.y * rr * sc.y, -60000.f), 60000.f);
    o.z = fminf(fmaxf(v.z * rr * sc.z, -60000.f), 60000.f);
    o.w = fminf(fmaxf(v.w * rr * sc.w, -60000.f), 60000.f);
    ((float4*)xs[i])[t] = o;
    __syncthreads();                     // xs[i] visible + red free for next row
  }
  __syncthreads();
  const int d0 = t * 4;
  float wl[4][4];
#pragma unroll
  for (int j = 0; j < 4; ++j) {
    const float4 t4 = *(const float4*)(w + (d0 + j) * 4);
    wl[j][0] = t4.x; wl[j][1] = t4.y; wl[j][2] = t4.z; wl[j][3] = t4.w;
  }
  const float4 cb4 = ((const float4*)cb)[t];
#pragma unroll
  for (int orow = 0; orow < 8; ++orow) {
    float o[4] = {0.f, 0.f, 0.f, 0.f};
#pragma unroll
    for (int k = 0; k < 4; ++k) {
      const float4 xv = ((const float4*)xs[orow + k])[t];
      o[0] += xv.x * wl[0][k]; o[1] += xv.y * wl[1][k];
      o[2] += xv.z * wl[2][k]; o[3] += xv.w * wl[3][k];
    }
    ushort4 st;
    { const float a = o[0] + cb4.x; st.x = f2bf(a * sigm(a)); }
    { const float a = o[1] + cb4.y; st.y = f2bf(a * sigm(a)); }
    { const float a = o[2] + cb4.z; st.z = f2bf(a * sigm(a)); }
    { const float a = o[3] + cb4.w; st.w = f2bf(a * sigm(a)); }
    *(ushort4*)(xc + (row0 + orow) * DMODEL + d0) = st;
  }
}

// ---------------- GEMM: C[M][NC] = A[M][K] @ BT[NC][K]^T  (bf16, f32 acc) ---------
// 256x256 tile, 8 waves (2M x 4N), per-wave 128x64 (acc[8][4]), BK=64.
// 8-phase schedule (T3+T4): per phase {4-8 ds_read || stage 1 slice (2 gl_lds16)
// -> s_barrier -> lgkmcnt(0)+sched_barrier -> setprio(1)+16 MFMA -> vmcnt(8)
// -> s_barrier}. Slices = 16KB (256 rows x 32k); 8 slots = 2buf x {A,B} x {ks0,ks1};
// stage lead 5-6 phases, tail peels vmcnt 8->4->0. T2 granule swizzle (R6-proven),
// L2 supertile decode. EPI==0: plain bf16 store (3072 cols). EPI==1: resid+f32.
template <int EPI, int NBN, int SBN>
__global__ __launch_bounds__(512) void gemm_bt(const unsigned short* __restrict__ A,
                                               const unsigned short* __restrict__ BT,
                                               unsigned short* __restrict__ ob,
                                               float* __restrict__ of,
                                               const float* __restrict__ resid) {
  __shared__ unsigned short As[2][2][8192];   // [buf][kslice][256*32]
  __shared__ unsigned short Bs[2][2][8192];
  const int tid = threadIdx.x;
  const int l = tid & 63;
  const int w = tid >> 6;            // wave 0..7
  const int wr = w >> 2, wc = w & 3; // 2M x 4N
  constexpr int NC = (EPI == 0) ? 3072 : 1024;

  // T1: XCD round-robin + per-XCD 4bm x SBN supertiles (bnS-inner); XB=16 bm/XCD
  constexpr int BPS = 4 * SBN;
  constexpr int NBNS = NBN / SBN;
  const int lin = blockIdx.y * NBN + blockIdx.x;
  const int xcd = lin & 7;
  const int g = lin >> 3;
  const int s = g / BPS;
  const int r = g - s * BPS;
  const int bmo = r / SBN;
  const int bno = r - bmo * SBN;
  const int bmS = s / NBNS;
  const int bnS = s - bmS * NBNS;
  const int bm = xcd * 16 + bmS * 4 + bmo;
  const int bn = bnS * SBN + bno;

  f32x4 acc[8][4];
#pragma unroll
  for (int m = 0; m < 8; ++m)
#pragma unroll
    for (int n = 0; n < 4; ++n) acc[m][n] = {0.f, 0.f, 0.f, 0.f};

  // staging: one gl_lds16 wave-call = 16 rows x 64B. lane l -> row l>>2, granule l&3
  // T2 pre-swizzled source granule, key=(row>>1)&3 = (l>>3)&3
  const int srcc = (((l & 3) ^ ((l >> 3) & 3)) * 8);
  const unsigned short* aG0 = A + ((long)(bm * 256 + w * 32 + (l >> 2))) * KDIM + srcc;
  const unsigned short* bG0 = BT + ((long)(bn * 256 + w * 32 + (l >> 2))) * KDIM + srcc;
  const int wL0 = w * 1024;          // wave-uniform LDS dest (elements)

#define STAGE_A(buf, ks, kofs)                                     \
  { gl_lds16(aG0 + (kofs),            &As[buf][ks][wL0]);          \
    gl_lds16(aG0 + (kofs) + 16*KDIM,  &As[buf][ks][wL0 + 512]); }
#define STAGE_B(buf, ks, kofs)                                     \
  { gl_lds16(bG0 + (kofs),            &Bs[buf][ks][wL0]);          \
    gl_lds16(bG0 + (kofs) + 16*KDIM,  &Bs[buf][ks][wL0 + 512]); }

  // read-side swizzled k-granule, key=(row>>1)&3 = (l>>1)&3
  const int eoff = (((l >> 4) ^ ((l >> 1) & 3)) * 8);
  const int aRowOff = (wr * 128 + (l & 15)) * 32 + eoff;   // + h*2048 + m*512
  const int bRowOff = (wc * 64 + (l & 15)) * 32 + eoff;    // + n*512

  bf16x8 bf[4];

#define PHASE(buf, ks, h, stg, vmn)                                            \
  {                                                                            \
    bf16x8 af[4];                                                              \
    _Pragma("unroll")                                                          \
    for (int m = 0; m < 4; ++m)                                                \
      af[m] = *(const bf16x8*)&As[buf][ks][aRowOff + (h) * 2048 + m * 512];    \
    if ((h) == 0) {                                                            \
      _Pragma("unroll")                                                        \
      for (int n = 0; n < 4; ++n)                                              \
        bf[n] = *(const bf16x8*)&Bs[buf][ks][bRowOff + n * 512];               \
    }                                                                          \
    stg;                                                                       \
    __builtin_amdgcn_s_barrier();                                              \
    asm volatile("s_waitcnt lgkmcnt(0)" ::: "memory");                         \
    __builtin_amdgcn_sched_barrier(0);                                         \
    __builtin_amdgcn_s_setprio(1);                                             \
    _Pragma("unroll")                                                          \
    for (int m = 0; m < 4; ++m)                                                \
      _Pragma("unroll")                                                        \
      for (int n = 0; n < 4; ++n)                                              \
        acc[(h) * 4 + m][n] = __builtin_amdgcn_mfma_f32_16x16x32_bf16(         \
            af[m], bf[n], acc[(h) * 4 + m][n], 0, 0, 0);                       \
    __builtin_amdgcn_s_setprio(0);                                             \
    asm volatile("s_waitcnt vmcnt(" vmn ")" ::: "memory");                     \
    __builtin_amdgcn_s_barrier();                                              \
    __builtin_amdgcn_sched_barrier(0);                                         \
  }

  // prologue: slices 0..5 = [t0.A0, t0.B0, t0.A1, t0.B1, t1.A0, t1.B0]
  STAGE_A(0, 0, 0);
  STAGE_B(0, 0, 0);
  STAGE_A(0, 1, 32);
  STAGE_B(0, 1, 32);
  STAGE_A(1, 0, 64);
  STAGE_B(1, 0, 64);
  asm volatile("s_waitcnt vmcnt(8)" ::: "memory");   // t0.A0,B0 landed
  __builtin_amdgcn_s_barrier();
  __builtin_amdgcn_sched_barrier(0);

  // main loop: tiles 0..13 (full staging). Per tile t:
  //  p0 stages A.ks1(t+1); p1: B.ks1(t+1); p2: A.ks0(t+2); p3: B.ks0(t+2)
  for (int t = 0; t < 14; ++t) {
    const int buf = t & 1, bufn = buf ^ 1;
    const int k1 = (t + 1) * 64 + 32;
    const int k2 = (t + 2) * 64;
    PHASE(buf, 0, 0, STAGE_A(bufn, 1, k1), "8");
    PHASE(buf, 0, 1, STAGE_B(bufn, 1, k1), "8");
    PHASE(buf, 1, 0, STAGE_A(buf, 0, k2), "8");
    PHASE(buf, 1, 1, STAGE_B(buf, 0, k2), "8");
  }
  // tile 14 (buf 0): stage last 2 slices (t15 ks1)
  PHASE(0, 0, 0, STAGE_A(1, 1, 15 * 64 + 32), "8");
  PHASE(0, 0, 1, STAGE_B(1, 1, 15 * 64 + 32), "8");
  PHASE(0, 1, 0, ((void)0), "8");
  PHASE(0, 1, 1, ((void)0), "4");
  // tile 15 (buf 1): no staging; drain
  PHASE(1, 0, 0, ((void)0), "4");
  PHASE(1, 0, 1, ((void)0), "0");
  PHASE(1, 1, 0, ((void)0), "0");
  PHASE(1, 1, 1, ((void)0), "0");
#undef PHASE
#undef STAGE_A
#undef STAGE_B

  const int rbase = bm * 256 + wr * 128;
  const int cbase = bn * 256 + wc * 64;
  const int lr4 = (l >> 4) * 4;
  const int lc16 = l & 15;

  if constexpr (EPI == 0) {
#pragma unroll
    for (int m = 0; m < 8; ++m)
#pragma unroll
      for (int n = 0; n < 4; ++n) {
        const int col = cbase + n * 16 + lc16;
#pragma unroll
        for (int j2 = 0; j2 < 4; ++j2) {
          const int row = rbase + m * 16 + lr4 + j2;
          ob[(long)row * NC + col] = f2bf(acc[m][n][j2]);
        }
      }
  } else {
#pragma unroll
    for (int m = 0; m < 8; ++m)
#pragma unroll
      for (int n = 0; n < 4; ++n) {
        const int col = cbase + n * 16 + lc16;
#pragma unroll
        for (int j2 = 0; j2 < 4; ++j2) {
          const int row = rbase + m * 16 + lr4 + j2;
          const long o = (long)row * NC + col;
          of[o] = resid[o] + acc[m][n][j2];
        }
      }
  }
}

// ------- scan pass 1: fused softplus(dt)+RoPE(v) from fusedb, stabilizer lm=0 -----
__global__ __launch_bounds__(256) void scan1_k(const unsigned short* __restrict__ fu,
                                               const float* __restrict__ dt_bias,
                                               const float2* __restrict__ tab,
                                               float* __restrict__ Llast,
                                               float* __restrict__ bout) {
  const int idx = blockIdx.x * 256 + threadIdx.x;   // B*NCHK*D = 131072
  const int d = idx & 1023;
  const int ch = (idx >> 10) & 31;
  const int b = idx >> 15;
  const long base = ((long)b * NSEQ + ch * CHUNKC) * 3072 + d;
  const float bias = dt_bias[d];
  const int f = d & 31;
  const bool hi = (d & 32) != 0;
  const int po = hi ? -32 : 32;
  float run = 0.f, s = 0.f, L = 0.f;
#pragma unroll 4
  for (int c = 0; c < CHUNKC; ++c) {
    const long o = base + (long)c * 3072;
    const float a = bf2f(fu[o]) + bias;
    const float e2 = exp2f(-LOG2E * fabsf(a));
    const float sp = fmaxf(a, 0.f) + 0.69314718f * log2f(1.f + e2);
    const float dtv = fminf(fmaxf(sp, 0.001f), 2.0f);
    const float own = bf2f(fu[o + 1024]);
    const float oth = bf2f(fu[o + 1024 + po]);
    const float2 cs = tab[(ch * CHUNKC + c) * 32 + f];
    const float vr = own * cs.x + (hi ? oth * cs.y : -oth * cs.y);
    run -= dtv;
    L = fminf(fmaxf(run, -20.f), 0.f);
    s += exp2f(-LOG2E * L) * (vr * dtv);
  }
  Llast[idx] = L;
  bout[idx] = exp2f(LOG2E * L) * s;
}

// ---------------- scan pass 2: cross-chunk scan per (b,d) -> carry ----------------
__global__ __launch_bounds__(256) void scan2_k(const float* __restrict__ Llast,
                                               const float* __restrict__ bout,
                                               float* __restrict__ carry) {
  const int idx = blockIdx.x * 256 + threadIdx.x;   // B*D = 4096
  const int d = idx & 1023;
  const int b = idx >> 10;
  const long base = (long)b * (NCHK * DMODEL) + d;
  float cd[NCHK];
  float run = 0.f, stab = -1e30f;
#pragma unroll
  for (int ch = 0; ch < NCHK; ++ch) {
    run += Llast[base + ch * DMODEL];
    cd[ch] = fminf(fmaxf(run, -80.f), 0.f);
    stab = fmaxf(stab, cd[ch]);
  }
  float acc = 0.f;
#pragma unroll
  for (int ch = 0; ch < NCHK; ++ch) {
    const float ncd = fminf(fmaxf(cd[ch] - stab, -20.f), 0.f);
    carry[base + ch * DMODEL] = acc * exp2f(LOG2E * ncd);
    acc += bout[base + ch * DMODEL] * exp2f(-LOG2E * ncd);
  }
}

// ------- scan pass 3: same front-end; writes final bf16 IN PLACE over v-segment ---
// partner reads are within the same 64-lane wave -> lockstep read-before-write safe.
__global__ __launch_bounds__(256) void scan3_k(unsigned short* fu,
                                               const float* __restrict__ dt_bias,
                                               const float2* __restrict__ tab,
                                               const float* __restrict__ carry) {
  const int idx = blockIdx.x * 256 + threadIdx.x;
  const int d = idx & 1023;
  const int ch = (idx >> 10) & 31;
  const int b = idx >> 15;
  const long base = ((long)b * NSEQ + ch * CHUNKC) * 3072 + d;
  const float bias = dt_bias[d];
  const int f = d & 31;
  const bool hi = (d & 32) != 0;
  const int po = hi ? -32 : 32;
  const float ce = carry[idx];
  float run = 0.f, s = 0.f;
#pragma unroll 4
  for (int c = 0; c < CHUNKC; ++c) {
    const long o = base + (long)c * 3072;
    const float a = bf2f(fu[o]) + bias;
    const float e2 = exp2f(-LOG2E * fabsf(a));
    const float sp = fmaxf(a, 0.f) + 0.69314718f * log2f(1.f + e2);
    const float dtv = fminf(fmaxf(sp, 0.001f), 2.0f);
    const float own = bf2f(fu[o + 1024]);
    const float oth = bf2f(fu[o + 1024 + po]);
    const float2 cs = tab[(ch * CHUNKC + c) * 32 + f];
    const float vr = own * cs.x + (hi ? oth * cs.y : -oth * cs.y);
    run -= dtv;
    const float L = fminf(fmaxf(run, -20.f), 0.f);
    s += exp2f(-LOG2E * L) * (vr * dtv);
    fu[o + 1024] = f2bf(exp2f(LOG2E * L) * (s + ce));
  }
}

// ---------------- head mix (16x16) * sigmoid(gate_raw) -> A2 bf16 ----------------
__global__ __launch_bounds__(256) void headmix_k(const unsigned short* __restrict__ fu,
                                                 const float* __restrict__ hm,
                                                 unsigned short* __restrict__ A2) {
  __shared__ float mixs[256];
  const int t = threadIdx.x;
  mixs[t] = hm[t];
  __syncthreads();
  const long row = (long)blockIdx.x * 4 + (t >> 6);
  const int dd = t & 63;
  const unsigned short* fv0 = fu + row * 3072 + 1024 + dd;   // final (over v)
  const unsigned short* gv0 = fu + row * 3072 + 2048 + dd;   // gate raw
  float fv[16];
#pragma unroll
  for (int h = 0; h < 16; ++h) fv[h] = bf2f(fv0[h * 64]);
#pragma unroll
  for (int m = 0; m < 16; ++m) {
    float o = 0.f;
#pragma unroll
    for (int h = 0; h < 16; ++h) o += fv[h] * mixs[h * 16 + m];
    A2[row * DMODEL + m * 64 + dd] = f2bf(o * sigm(bf2f(gv0[m * 64])));
  }
}

extern "C" void kernel_launch(void* const* d_in, const int* in_sizes, int n_in,
                              void* d_out, int out_size, void* d_ws, size_t ws_size,
                              hipStream_t stream) {
  const float* x        = (const float*)d_in[0];
  const float* nscale   = (const float*)d_in[1];
  const float* conv_w   = (const float*)d_in[2];
  const float* conv_b   = (const float*)d_in[3];
  const float* in_proj  = (const float*)d_in[4];
  const float* dt_bias  = (const float*)d_in[5];
  const float* head_mix = (const float*)d_in[6];
  const float* out_proj = (const float*)d_in[7];
  float* out = (float*)d_out;

  char* p = (char*)d_ws;
  unsigned short* W1T = (unsigned short*)p; p += (size_t)3072 * 1024 * 2;
  unsigned short* W2T = (unsigned short*)p; p += (size_t)1024 * 1024 * 2;
  float2* tab  = (float2*)p; p += (size_t)NSEQ * 32 * sizeof(float2);
  float* Llast = (float*)p;  p += (size_t)131072 * 4;
  float* bout  = (float*)p;  p += (size_t)131072 * 4;
  float* carry = (float*)p;  p += (size_t)131072 * 4;
  unsigned short* fusedb = (unsigned short*)p; p += (size_t)TOK * 3072 * 2;
  unsigned short* xc     = (unsigned short*)p; p += (size_t)TOK * DMODEL * 2; // reused: A2

  transpose_bf16_k<<<dim3(96, 32), dim3(32, 8), 0, stream>>>(in_proj, W1T, 1024, 3072);
  transpose_bf16_k<<<dim3(32, 32), dim3(32, 8), 0, stream>>>(out_proj, W2T, 1024, 1024);
  ropetab_k<<<1024, 256, 0, stream>>>(tab);
  rmsconv_k<<<TOK / 8, 256, 0, stream>>>(x, nscale, conv_w, conv_b, xc);

  gemm_bt<0, 12, 6><<<dim3(12, 128), 512, 0, stream>>>(xc, W1T, fusedb, nullptr, nullptr);
  scan1_k<<<512, 256, 0, stream>>>(fusedb, dt_bias, tab, Llast, bout);
  scan2_k<<<16, 256, 0, stream>>>(Llast, bout, carry);
  scan3_k<<<512, 256, 0, stream>>>(fusedb, dt_bias, tab, carry);
  headmix_k<<<TOK / 4, 256, 0, stream>>>(fusedb, head_mix, xc /* A2 */);
  gemm_bt<1, 4, 4><<<dim3(4, 128), 512, 0, stream>>>(xc, W2T, nullptr, out, x);
}

// Round 8
// 622.993 us; speedup vs baseline: 1.0529x; 1.0529x over previous
//
#include <hip/hip_runtime.h>

#define TOK 32768          // B*N
#define DMODEL 1024
#define NSEQ 8192
#define NCHK 32            // chunks per sequence
#define CHUNKC 256
#define KDIM 1024
#define LOG2E 1.44269504f

typedef __attribute__((ext_vector_type(8))) short bf16x8;
typedef __attribute__((ext_vector_type(4))) float f32x4;

__device__ __forceinline__ unsigned short f2bf(float f) {
  unsigned u = __float_as_uint(f);
  u += 0x7fffu + ((u >> 16) & 1u);
  return (unsigned short)(u >> 16);
}
__device__ __forceinline__ float bf2f(unsigned short h) {
  return __uint_as_float(((unsigned)h) << 16);
}
__device__ __forceinline__ float sigm(float x) {   // sigmoid via exp2+rcp
  return __builtin_amdgcn_rcpf(1.f + exp2f(-LOG2E * x));
}

typedef __attribute__((address_space(3))) unsigned int lds_u32_t;
typedef const __attribute__((address_space(1))) unsigned int glb_u32_t;

__device__ __forceinline__ void gl_lds16(const void* g, void* l) {
  __builtin_amdgcn_global_load_lds((glb_u32_t*)g, (lds_u32_t*)l, 16, 0, 0);
}

// ---------------- prep: W1T/W2T transpose->bf16 + RoPE table, one kernel ----------
__global__ __launch_bounds__(256) void prep_k(const float* __restrict__ w1,
                                              const float* __restrict__ w2,
                                              unsigned short* __restrict__ w1t,
                                              unsigned short* __restrict__ w2t,
                                              float2* __restrict__ tab) {
  __shared__ float tile[32][33];
  const int bid = blockIdx.x;
  const int t = threadIdx.x;
  if (bid < 4096) {   // transpose W[R=1024][C] -> WT[C][1024]
    const float* in;
    unsigned short* out;
    int c0, r0;
    if (bid < 3072) { in = w1; out = w1t; c0 = (bid % 96) * 32; r0 = (bid / 96) * 32; }
    else            { in = w2; out = w2t; c0 = ((bid - 3072) & 31) * 32; r0 = ((bid - 3072) >> 5) * 32; }
    const int C = (bid < 3072) ? 3072 : 1024;
    const int tx = t & 31, ty = t >> 5;
#pragma unroll
    for (int i = 0; i < 32; i += 8)
      tile[ty + i][tx] = in[(long)(r0 + ty + i) * C + c0 + tx];
    __syncthreads();
#pragma unroll
    for (int i = 0; i < 32; i += 8)
      out[(long)(c0 + ty + i) * 1024 + r0 + tx] = f2bf(tile[tx][ty + i]);
  } else {            // RoPE table: 8192*32 entries
    const int i = (bid - 4096) * 256 + t;
    const int f = i & 31, n = i >> 5;
    const float invf = exp2f(-(float)f * (13.287712379549449f / 32.0f));
    const float ang = (float)n * invf;
    tab[i] = make_float2(cosf(ang), sinf(ang));
  }
}

// ------- fused RMSNorm + depthwise causal conv(K=4) + SiLU -> bf16 (1 barrier) ----
__global__ __launch_bounds__(256) void rmsconv_k(const float* __restrict__ x,
                                                 const float* __restrict__ scale,
                                                 const float* __restrict__ w,
                                                 const float* __restrict__ cb,
                                                 unsigned short* __restrict__ xc) {
  __shared__ float red[11][4];
  const int t = threadIdx.x;
  const long row0 = (long)blockIdx.x * 8;
  const bool seqstart = ((row0 & (NSEQ - 1)) == 0);
  const float4 sc = ((const float4*)scale)[t];
  float4 vr[11];
#pragma unroll
  for (int i = 0; i < 11; ++i) {
    if (i < 3 && seqstart) {
      vr[i] = make_float4(0.f, 0.f, 0.f, 0.f);
    } else {
      vr[i] = ((const float4*)(x + (row0 - 3 + i) * DMODEL))[t];
    }
    float ss = vr[i].x * vr[i].x + vr[i].y * vr[i].y + vr[i].z * vr[i].z + vr[i].w * vr[i].w;
#pragma unroll
    for (int off = 32; off > 0; off >>= 1) ss += __shfl_down(ss, off);
    if ((t & 63) == 0) red[i][t >> 6] = ss;
  }
  __syncthreads();
#pragma unroll
  for (int i = 0; i < 11; ++i) {
    const float tot = red[i][0] + red[i][1] + red[i][2] + red[i][3];
    const float rr = rsqrtf(tot * (1.0f / DMODEL) + 1e-6f);
    vr[i].x = fminf(fmaxf(vr[i].x * rr * sc.x, -60000.f), 60000.f);
    vr[i].y = fminf(fmaxf(vr[i].y * rr * sc.y, -60000.f), 60000.f);
    vr[i].z = fminf(fmaxf(vr[i].z * rr * sc.z, -60000.f), 60000.f);
    vr[i].w = fminf(fmaxf(vr[i].w * rr * sc.w, -60000.f), 60000.f);
  }
  const int d0 = t * 4;
  float wl[4][4];
#pragma unroll
  for (int j = 0; j < 4; ++j) {
    const float4 t4 = *(const float4*)(w + (d0 + j) * 4);
    wl[j][0] = t4.x; wl[j][1] = t4.y; wl[j][2] = t4.z; wl[j][3] = t4.w;
  }
  const float4 cb4 = ((const float4*)cb)[t];
#pragma unroll
  for (int orow = 0; orow < 8; ++orow) {
    float o[4] = {0.f, 0.f, 0.f, 0.f};
#pragma unroll
    for (int k = 0; k < 4; ++k) {
      const float4 xv = vr[orow + k];
      o[0] += xv.x * wl[0][k]; o[1] += xv.y * wl[1][k];
      o[2] += xv.z * wl[2][k]; o[3] += xv.w * wl[3][k];
    }
    ushort4 st;
    { const float a = o[0] + cb4.x; st.x = f2bf(a * sigm(a)); }
    { const float a = o[1] + cb4.y; st.y = f2bf(a * sigm(a)); }
    { const float a = o[2] + cb4.z; st.z = f2bf(a * sigm(a)); }
    { const float a = o[3] + cb4.w; st.w = f2bf(a * sigm(a)); }
    *(ushort4*)(xc + (row0 + orow) * DMODEL + d0) = st;
  }
}

// ---------------- GEMM1: 256x256 tile, 8-phase, derived counted waits -------------
// 8 waves (2M x 4N), per-wave 128x64 (acc[8][4]), BK=64, slices=16KB, 8 slots.
// Waits: vmcnt(8) at END of p1/p3 only (covers next 2 phases' slices exactly);
// tail peels 8->4->0. T2 granule swizzle, L2 supertile decode. Plain bf16 store.
template <int NBN, int SBN>
__global__ __launch_bounds__(512) void gemm8_k(const unsigned short* __restrict__ A,
                                               const unsigned short* __restrict__ BT,
                                               unsigned short* __restrict__ ob) {
  __shared__ unsigned short As[2][2][8192];   // [buf][kslice][256*32]
  __shared__ unsigned short Bs[2][2][8192];
  const int tid = threadIdx.x;
  const int l = tid & 63;
  const int w = tid >> 6;            // wave 0..7
  const int wr = w >> 2, wc = w & 3; // 2M x 4N
  constexpr int NC = 3072;

  constexpr int BPS = 4 * SBN;
  constexpr int NBNS = NBN / SBN;
  const int lin = blockIdx.y * NBN + blockIdx.x;
  const int xcd = lin & 7;
  const int g = lin >> 3;
  const int s = g / BPS;
  const int r = g - s * BPS;
  const int bmo = r / SBN;
  const int bno = r - bmo * SBN;
  const int bmS = s / NBNS;
  const int bnS = s - bmS * NBNS;
  const int bm = xcd * 16 + bmS * 4 + bmo;
  const int bn = bnS * SBN + bno;

  f32x4 acc[8][4];
#pragma unroll
  for (int m = 0; m < 8; ++m)
#pragma unroll
    for (int n = 0; n < 4; ++n) acc[m][n] = {0.f, 0.f, 0.f, 0.f};

  const int srcc = (((l & 3) ^ ((l >> 3) & 3)) * 8);
  const unsigned short* aG0 = A + ((long)(bm * 256 + w * 32 + (l >> 2))) * KDIM + srcc;
  const unsigned short* bG0 = BT + ((long)(bn * 256 + w * 32 + (l >> 2))) * KDIM + srcc;
  const int wL0 = w * 1024;

#define STAGE_A(buf, ks, kofs)                                     \
  { gl_lds16(aG0 + (kofs),            &As[buf][ks][wL0]);          \
    gl_lds16(aG0 + (kofs) + 16*KDIM,  &As[buf][ks][wL0 + 512]); }
#define STAGE_B(buf, ks, kofs)                                     \
  { gl_lds16(bG0 + (kofs),            &Bs[buf][ks][wL0]);          \
    gl_lds16(bG0 + (kofs) + 16*KDIM,  &Bs[buf][ks][wL0 + 512]); }

  const int eoff = (((l >> 4) ^ ((l >> 1) & 3)) * 8);
  const int aRowOff = (wr * 128 + (l & 15)) * 32 + eoff;
  const int bRowOff = (wc * 64 + (l & 15)) * 32 + eoff;

  bf16x8 bf[4];

#define VM8 asm volatile("s_waitcnt vmcnt(8)" ::: "memory")
#define VM4 asm volatile("s_waitcnt vmcnt(4)" ::: "memory")
#define VM0 asm volatile("s_waitcnt vmcnt(0)" ::: "memory")
#define NOW ((void)0)

#define PHASE(buf, ks, h, stg, wt)                                             \
  {                                                                            \
    bf16x8 af[4];                                                              \
    _Pragma("unroll")                                                          \
    for (int m = 0; m < 4; ++m)                                                \
      af[m] = *(const bf16x8*)&As[buf][ks][aRowOff + (h) * 2048 + m * 512];    \
    if ((h) == 0) {                                                            \
      _Pragma("unroll")                                                        \
      for (int n = 0; n < 4; ++n)                                              \
        bf[n] = *(const bf16x8*)&Bs[buf][ks][bRowOff + n * 512];               \
    }                                                                          \
    stg;                                                                       \
    __builtin_amdgcn_s_barrier();                                              \
    asm volatile("s_waitcnt lgkmcnt(0)" ::: "memory");                         \
    __builtin_amdgcn_sched_barrier(0);                                         \
    __builtin_amdgcn_s_setprio(1);                                             \
    _Pragma("unroll")                                                          \
    for (int m = 0; m < 4; ++m)                                                \
      _Pragma("unroll")                                                        \
      for (int n = 0; n < 4; ++n)                                              \
        acc[(h) * 4 + m][n] = __builtin_amdgcn_mfma_f32_16x16x32_bf16(         \
            af[m], bf[n], acc[(h) * 4 + m][n], 0, 0, 0);                       \
    __builtin_amdgcn_s_setprio(0);                                             \
    wt;                                                                        \
    __builtin_amdgcn_s_barrier();                                              \
    __builtin_amdgcn_sched_barrier(0);                                         \
  }

  // prologue: slices [t0.A0, t0.B0, t0.A1, t0.B1, t1.A0, t1.B0]
  STAGE_A(0, 0, 0);
  STAGE_B(0, 0, 0);
  STAGE_A(0, 1, 32);
  STAGE_B(0, 1, 32);
  STAGE_A(1, 0, 64);
  STAGE_B(1, 0, 64);
  VM8;                               // t0.A0,B0 landed
  __builtin_amdgcn_s_barrier();
  __builtin_amdgcn_sched_barrier(0);

  // main: tiles 0..13. p0 stages (t+1).A1, p1 (t+1).B1, p2 (t+2).A0, p3 (t+2).B0.
  // waits at end of p1/p3 only (ledger: exactly covers next 2 phases' slices).
  for (int t = 0; t < 14; ++t) {
    const int buf = t & 1, bufn = buf ^ 1;
    const int k1 = (t + 1) * 64 + 32;
    const int k2 = (t + 2) * 64;
    PHASE(buf, 0, 0, STAGE_A(bufn, 1, k1), NOW);
    PHASE(buf, 0, 1, STAGE_B(bufn, 1, k1), VM8);
    PHASE(buf, 1, 0, STAGE_A(buf, 0, k2), NOW);
    PHASE(buf, 1, 1, STAGE_B(buf, 0, k2), VM8);
  }
  // tile 14 (buf 0): stage last 2 slices (t15 ks1), then drain
  PHASE(0, 0, 0, STAGE_A(1, 1, 992), NOW);
  PHASE(0, 0, 1, STAGE_B(1, 1, 992), VM8);
  PHASE(0, 1, 0, NOW, NOW);
  PHASE(0, 1, 1, NOW, VM4);
  // tile 15 (buf 1)
  PHASE(1, 0, 0, NOW, NOW);
  PHASE(1, 0, 1, NOW, VM0);
  PHASE(1, 1, 0, NOW, NOW);
  PHASE(1, 1, 1, NOW, NOW);
#undef PHASE
#undef STAGE_A
#undef STAGE_B

  const int rbase = bm * 256 + wr * 128;
  const int cbase = bn * 256 + wc * 64;
  const int lr4 = (l >> 4) * 4;
  const int lc16 = l & 15;
#pragma unroll
  for (int m = 0; m < 8; ++m)
#pragma unroll
    for (int n = 0; n < 4; ++n) {
      const int col = cbase + n * 16 + lc16;
#pragma unroll
      for (int j2 = 0; j2 < 4; ++j2) {
        const int row = rbase + m * 16 + lr4 + j2;
        ob[(long)row * NC + col] = f2bf(acc[m][n][j2]);
      }
    }
}

// ---------------- GEMM2 (R6-proven): 128x256 tile, 3-slot BK=32 ring --------------
template <int NBN, int SBN>
__global__ __launch_bounds__(256) void gemm2_k(const unsigned short* __restrict__ A,
                                               const unsigned short* __restrict__ BT,
                                               float* __restrict__ of,
                                               const float* __restrict__ resid) {
  __shared__ unsigned short As[3][128 * 32];
  __shared__ unsigned short Bs[3][256 * 32];
  const int tid = threadIdx.x;
  const int l = tid & 63;
  const int w = tid >> 6;
  constexpr int NC = 1024;
  constexpr int NKT = KDIM / 32;

  constexpr int BPS = 4 * SBN;
  constexpr int NBNS = NBN / SBN;
  const int lin = blockIdx.y * NBN + blockIdx.x;
  const int xcd = lin & 7;
  const int g = lin >> 3;
  const int s = g / BPS;
  const int r = g - s * BPS;
  const int bmo = r / SBN;
  const int bno = r - bmo * SBN;
  const int bmS = s / NBNS;
  const int bnS = s - bmS * NBNS;
  const int bm = xcd * 32 + bmS * 4 + bmo;
  const int bn = bnS * SBN + bno;

  f32x4 acc[8][4];
#pragma unroll
  for (int m = 0; m < 8; ++m)
#pragma unroll
    for (int n = 0; n < 4; ++n) acc[m][n] = {0.f, 0.f, 0.f, 0.f};

  const int srcc = (((l & 3) ^ ((l >> 3) & 3)) * 8);
  const unsigned short* aG0 = A + ((long)(bm * 128 + w * 32 + (l >> 2))) * KDIM + srcc;
  const unsigned short* bG0 = BT + ((long)(bn * 256 + w * 64 + (l >> 2))) * KDIM + srcc;
  const int aLo = (w * 32) * 32;
  const int bLo = (w * 64) * 32;

#define STAGE(buf, k0)                                           \
  {                                                              \
    gl_lds16(aG0 + (k0),             &As[buf][aLo]);             \
    gl_lds16(aG0 + (k0) + 16 * KDIM, &As[buf][aLo + 512]);       \
    gl_lds16(bG0 + (k0),             &Bs[buf][bLo]);             \
    gl_lds16(bG0 + (k0) + 16 * KDIM, &Bs[buf][bLo + 512]);       \
    gl_lds16(bG0 + (k0) + 32 * KDIM, &Bs[buf][bLo + 1024]);      \
    gl_lds16(bG0 + (k0) + 48 * KDIM, &Bs[buf][bLo + 1536]);      \
  }

  const int eoff = (((l >> 4) ^ ((l >> 1) & 3)) * 8);
  const int arow0 = (l & 15) * 32 + eoff;
  const int brow0 = (w * 64 + (l & 15)) * 32 + eoff;

  auto compute = [&](int cur) {
    const unsigned short* Ab = &As[cur][0];
    const unsigned short* Bb = &Bs[cur][0];
    bf16x8 af[8], bfr[4];
#pragma unroll
    for (int m = 0; m < 8; ++m) af[m] = *(const bf16x8*)&Ab[arow0 + m * 512];
#pragma unroll
    for (int n = 0; n < 4; ++n) bfr[n] = *(const bf16x8*)&Bb[brow0 + n * 512];
    __builtin_amdgcn_s_setprio(1);
#pragma unroll
    for (int m = 0; m < 8; ++m)
#pragma unroll
      for (int n = 0; n < 4; ++n)
        acc[m][n] = __builtin_amdgcn_mfma_f32_16x16x32_bf16(af[m], bfr[n], acc[m][n], 0, 0, 0);
    __builtin_amdgcn_s_setprio(0);
  };

  STAGE(0, 0);
  STAGE(1, 32);
  asm volatile("s_waitcnt vmcnt(6)" ::: "memory");
  int cur = 0, nxt = 2;
  for (int t = 0; t < NKT - 2; ++t) {
    __builtin_amdgcn_s_barrier();
    __builtin_amdgcn_sched_barrier(0);
    STAGE(nxt, (t + 2) * 32);
    compute(cur);
    asm volatile("s_waitcnt vmcnt(6)" ::: "memory");
    cur = (cur == 2) ? 0 : cur + 1;
    nxt = (nxt == 2) ? 0 : nxt + 1;
  }
  __builtin_amdgcn_s_barrier();
  __builtin_amdgcn_sched_barrier(0);
  compute(cur);
  asm volatile("s_waitcnt vmcnt(0)" ::: "memory");
  cur = (cur == 2) ? 0 : cur + 1;
  __builtin_amdgcn_s_barrier();
  __builtin_amdgcn_sched_barrier(0);
  compute(cur);
#undef STAGE

  const int rbase = bm * 128;
  const int cbase = bn * 256 + w * 64;
  const int lr4 = (l >> 4) * 4;
  const int lc16 = l & 15;
#pragma unroll
  for (int m = 0; m < 8; ++m)
#pragma unroll
    for (int n = 0; n < 4; ++n) {
      const int col = cbase + n * 16 + lc16;
#pragma unroll
      for (int j2 = 0; j2 < 4; ++j2) {
        const int row = rbase + m * 16 + lr4 + j2;
        const long o = (long)row * NC + col;
        of[o] = resid[o] + acc[m][n][j2];
      }
    }
}

// ------- scan pass 1: fused softplus(dt)+RoPE(v) from fusedb, stabilizer lm=0 -----
__global__ __launch_bounds__(256) void scan1_k(const unsigned short* __restrict__ fu,
                                               const float* __restrict__ dt_bias,
                                               const float2* __restrict__ tab,
                                               float* __restrict__ Llast,
                                               float* __restrict__ bout) {
  const int idx = blockIdx.x * 256 + threadIdx.x;   // B*NCHK*D = 131072
  const int d = idx & 1023;
  const int ch = (idx >> 10) & 31;
  const int b = idx >> 15;
  const long base = ((long)b * NSEQ + ch * CHUNKC) * 3072 + d;
  const float bias = dt_bias[d];
  const int f = d & 31;
  const bool hi = (d & 32) != 0;
  const int po = hi ? -32 : 32;
  float run = 0.f, s = 0.f, L = 0.f;
#pragma unroll 4
  for (int c = 0; c < CHUNKC; ++c) {
    const long o = base + (long)c * 3072;
    const float a = bf2f(fu[o]) + bias;
    const float e2 = exp2f(-LOG2E * fabsf(a));
    const float sp = fmaxf(a, 0.f) + 0.69314718f * log2f(1.f + e2);
    const float dtv = fminf(fmaxf(sp, 0.001f), 2.0f);
    const float own = bf2f(fu[o + 1024]);
    const float oth = bf2f(fu[o + 1024 + po]);
    const float2 cs = tab[(ch * CHUNKC + c) * 32 + f];
    const float vr = own * cs.x + (hi ? oth * cs.y : -oth * cs.y);
    run -= dtv;
    L = fminf(fmaxf(run, -20.f), 0.f);
    s += exp2f(-LOG2E * L) * (vr * dtv);
  }
  Llast[idx] = L;
  bout[idx] = exp2f(LOG2E * L) * s;
}

// ---------------- scan pass 2: cross-chunk scan per (b,d) -> carry ----------------
__global__ __launch_bounds__(256) void scan2_k(const float* __restrict__ Llast,
                                               const float* __restrict__ bout,
                                               float* __restrict__ carry) {
  const int idx = blockIdx.x * 256 + threadIdx.x;   // B*D = 4096
  const int d = idx & 1023;
  const int b = idx >> 10;
  const long base = (long)b * (NCHK * DMODEL) + d;
  float cd[NCHK];
  float run = 0.f, stab = -1e30f;
#pragma unroll
  for (int ch = 0; ch < NCHK; ++ch) {
    run += Llast[base + ch * DMODEL];
    cd[ch] = fminf(fmaxf(run, -80.f), 0.f);
    stab = fmaxf(stab, cd[ch]);
  }
  float acc = 0.f;
#pragma unroll
  for (int ch = 0; ch < NCHK; ++ch) {
    const float ncd = fminf(fmaxf(cd[ch] - stab, -20.f), 0.f);
    carry[base + ch * DMODEL] = acc * exp2f(LOG2E * ncd);
    acc += bout[base + ch * DMODEL] * exp2f(-LOG2E * ncd);
  }
}

// ------- scan pass 3: same front-end; writes final bf16 IN PLACE over v-segment ---
__global__ __launch_bounds__(256) void scan3_k(unsigned short* fu,
                                               const float* __restrict__ dt_bias,
                                               const float2* __restrict__ tab,
                                               const float* __restrict__ carry) {
  const int idx = blockIdx.x * 256 + threadIdx.x;
  const int d = idx & 1023;
  const int ch = (idx >> 10) & 31;
  const int b = idx >> 15;
  const long base = ((long)b * NSEQ + ch * CHUNKC) * 3072 + d;
  const float bias = dt_bias[d];
  const int f = d & 31;
  const bool hi = (d & 32) != 0;
  const int po = hi ? -32 : 32;
  const float ce = carry[idx];
  float run = 0.f, s = 0.f;
#pragma unroll 4
  for (int c = 0; c < CHUNKC; ++c) {
    const long o = base + (long)c * 3072;
    const float a = bf2f(fu[o]) + bias;
    const float e2 = exp2f(-LOG2E * fabsf(a));
    const float sp = fmaxf(a, 0.f) + 0.69314718f * log2f(1.f + e2);
    const float dtv = fminf(fmaxf(sp, 0.001f), 2.0f);
    const float own = bf2f(fu[o + 1024]);
    const float oth = bf2f(fu[o + 1024 + po]);
    const float2 cs = tab[(ch * CHUNKC + c) * 32 + f];
    const float vr = own * cs.x + (hi ? oth * cs.y : -oth * cs.y);
    run -= dtv;
    const float L = fminf(fmaxf(run, -20.f), 0.f);
    s += exp2f(-LOG2E * L) * (vr * dtv);
    fu[o + 1024] = f2bf(exp2f(LOG2E * L) * (s + ce));
  }
}

// ---------------- head mix (16x16) * sigmoid(gate_raw) -> A2 bf16 ----------------
__global__ __launch_bounds__(256) void headmix_k(const unsigned short* __restrict__ fu,
                                                 const float* __restrict__ hm,
                                                 unsigned short* __restrict__ A2) {
  __shared__ float mixs[256];
  const int t = threadIdx.x;
  mixs[t] = hm[t];
  __syncthreads();
  const long row = (long)blockIdx.x * 4 + (t >> 6);
  const int dd = t & 63;
  const unsigned short* fv0 = fu + row * 3072 + 1024 + dd;   // final (over v)
  const unsigned short* gv0 = fu + row * 3072 + 2048 + dd;   // gate raw
  float fv[16];
#pragma unroll
  for (int h = 0; h < 16; ++h) fv[h] = bf2f(fv0[h * 64]);
#pragma unroll
  for (int m = 0; m < 16; ++m) {
    float o = 0.f;
#pragma unroll
    for (int h = 0; h < 16; ++h) o += fv[h] * mixs[h * 16 + m];
    A2[row * DMODEL + m * 64 + dd] = f2bf(o * sigm(bf2f(gv0[m * 64])));
  }
}

extern "C" void kernel_launch(void* const* d_in, const int* in_sizes, int n_in,
                              void* d_out, int out_size, void* d_ws, size_t ws_size,
                              hipStream_t stream) {
  const float* x        = (const float*)d_in[0];
  const float* nscale   = (const float*)d_in[1];
  const float* conv_w   = (const float*)d_in[2];
  const float* conv_b   = (const float*)d_in[3];
  const float* in_proj  = (const float*)d_in[4];
  const float* dt_bias  = (const float*)d_in[5];
  const float* head_mix = (const float*)d_in[6];
  const float* out_proj = (const float*)d_in[7];
  float* out = (float*)d_out;

  char* p = (char*)d_ws;
  unsigned short* W1T = (unsigned short*)p; p += (size_t)3072 * 1024 * 2;
  unsigned short* W2T = (unsigned short*)p; p += (size_t)1024 * 1024 * 2;
  float2* tab  = (float2*)p; p += (size_t)NSEQ * 32 * sizeof(float2);
  float* Llast = (float*)p;  p += (size_t)131072 * 4;
  float* bout  = (float*)p;  p += (size_t)131072 * 4;
  float* carry = (float*)p;  p += (size_t)131072 * 4;
  unsigned short* fusedb = (unsigned short*)p; p += (size_t)TOK * 3072 * 2;
  unsigned short* xc     = (unsigned short*)p; p += (size_t)TOK * DMODEL * 2; // reused: A2

  prep_k<<<5120, 256, 0, stream>>>(in_proj, out_proj, W1T, W2T, tab);
  rmsconv_k<<<TOK / 8, 256, 0, stream>>>(x, nscale, conv_w, conv_b, xc);

  gemm8_k<12, 6><<<dim3(12, 128), 512, 0, stream>>>(xc, W1T, fusedb);
  scan1_k<<<512, 256, 0, stream>>>(fusedb, dt_bias, tab, Llast, bout);
  scan2_k<<<16, 256, 0, stream>>>(Llast, bout, carry);
  scan3_k<<<512, 256, 0, stream>>>(fusedb, dt_bias, tab, carry);
  headmix_k<<<TOK / 4, 256, 0, stream>>>(fusedb, head_mix, xc /* A2 */);
  gemm2_k<4, 4><<<dim3(4, 256), 256, 0, stream>>>(xc, W2T, out, x);
}